// Round 9
// baseline (972.949 us; speedup 1.0000x reference)
//
#include <hip/hip_runtime.h>
#include <math.h>
#include <stdint.h>

#define NTAGS 512
#define SEQL  512
#define BATCH 64
#define START_TAG 510
#define STOP_TAG  511
#define NEG_INF  -10000.0f

// R0's proven machine (64 chain blocks x 8 waves x 1 row/wave, 8 replicas, 4-deep poll,
// LDS rebroadcast, 1 barrier/step) with the chain arithmetic in FP64 + early exit.
// Why fp64: the map w' = (Ew)./rowmax(E.*w) has Jacobian gain ~1e2 at its fixed point, so
// fp32 rounding sustains a noise orbit with consecutive diffs >3e-5 (R3-R5 exits never
// fired). fp64 noise floor ~3e-14 << the 1e-9 exit test, and contraction ~0.06-0.12/step
// (lognormal iid matrix) fires it at s~8-20. No-fire => full 512 fp64 steps (correct).
#define NBCH  64                // chain blocks: block b owns rows [8b,8b+8), wave w row 8b+w
#define NBLK  128               // + 64 numerator blocks (bid-64 == batch)
#define BT    512
#define ROWS  8
#define REPS  8                 // slot replicas; chain block polls replica bid&7
#define CONV_EPS 1e-9

// ws layout (bytes) — 65792 total, the R0-proven footprint.
#define WS_NUM_OFF  0           // float numerator accumulator
#define WS_DONE_OFF 8           // int: numerator blocks retired
#define WS_SLOT_OFF 256         // u64 slots [2][REPS][NTAGS]: fp64 bits, level-tag in mantissa
                                // LSB. tag(L) = ((L+1)>>1)&1 alternates per reuse of each
                                // depth-2 half and is 1 on first use => memset-0 never
                                // false-fires (R7-proven formula). 8B atomic = tear-free.
#define WS_BYTES    (WS_SLOT_OFF + 2 * REPS * NTAGS * 8)

#define AGLD(p)   __hip_atomic_load((p),      __ATOMIC_RELAXED, __HIP_MEMORY_SCOPE_AGENT)
#define AGST(p,v) __hip_atomic_store((p),(v), __ATOMIC_RELAXED, __HIP_MEMORY_SCOPE_AGENT)

__global__ __launch_bounds__(BT) void crf_fused(
    const float* __restrict__ inputs, const int* __restrict__ tags,
    const float* __restrict__ trans, void* __restrict__ ws,
    float* __restrict__ out)
{
    __shared__ double wlds[2][NTAGS];       // 8 KB ping-pong of w = exp(fv) (fp64)
    __shared__ int    conv[2][ROWS];        // [phase][wave] — double-buffered across the
                                            // single per-step barrier (R4-proven, race-free)

    const int tid  = threadIdx.x;
    const int bid  = blockIdx.x;
    const int lane = tid & 63;
    const int wave = tid >> 6;

    float*    numacc  = (float*)((char*)ws + WS_NUM_OFF);
    int*      numdone = (int*)  ((char*)ws + WS_DONE_OFF);
    uint64_t* slots   = (uint64_t*)((char*)ws + WS_SLOT_OFF);

    // ================= numerator blocks: bid in [64,128), batch bid-64 (off the chain) =====
    if (bid >= NBCH) {
        const int    b   = bid - NBCH;
        const int*   tg  = tags + b * SEQL;
        const float* inb = inputs + (size_t)b * SEQL * NTAGS;
        float ns;
        if (tid > 0) {
            const int cur = tg[tid], prev = tg[tid - 1];
            ns = trans[cur * NTAGS + prev] + inb[(size_t)(tid - 1) * NTAGS + cur];
        } else {
            ns = trans[tg[0] * NTAGS + START_TAG] + trans[STOP_TAG * NTAGS + tg[SEQL - 1]];
        }
        #pragma unroll
        for (int off = 32; off; off >>= 1) ns += __shfl_xor(ns, off);
        if (lane == 0) atomicAdd(numacc, ns);
        __builtin_amdgcn_s_waitcnt(0);      // RMW retired at coherence point
        __syncthreads();                    // all 8 waves done
        if (tid == 0) atomicAdd(numdone, 1);
        return;
    }

    // ================= chain block: row 8*bid + wave (R0 shape) ============================
    const int myrow = bid * ROWS + wave;
    const int rep   = bid & (REPS - 1);

    // transition row in EXP space, fp64: treg[q] = exp((double)T[myrow][lane+64q] + shift).
    // START row is uniformly -1e4 -> shift to exp(0)=1 (w'=p/q invariant to uniform row
    // scale; exp-space form validated absmax=0 across R1-R5,R7,R8). STOP column -> exp(-1e4)=0.
    double treg[8];
    {
        const float* trow  = trans + (size_t)myrow * NTAGS;
        const double shift = (myrow == START_TAG) ? -(double)NEG_INF : 0.0;
        #pragma unroll
        for (int q = 0; q < 8; ++q)
            treg[q] = exp((double)trow[lane + 64 * q] + shift);  // coalesced 256B/wave
    }

    // w_0: one-hot at START (level 0 never published)
    wlds[0][tid] = (tid == START_TAG) ? 1.0 : 0.0;
    wlds[1][tid] = 0.0;
    __syncthreads();

    int sel = 0;    // buffer holding the final w at exit (full run: 512 even -> buffer 0)

    for (int s = 0; s < SEQL; ++s) {
        const int      ph   = s & 1, nxt = ph ^ 1;               // wlds[ph] = w_s
        const uint64_t tag  = (uint64_t)(((s + 2) >> 1) & 1);    // tag(L=s+1) = ((L+1)>>1)&1
        uint64_t* pubbase = slots + (size_t)nxt * REPS * NTAGS;
        uint64_t* myslot  = slots + ((size_t)nxt * REPS + rep) * NTAGS + tid;

        // early probe: overlaps compute + publish (others' s+1 may already have arrived)
        uint64_t p = AGLD(myslot);

        // ---- my row: t = w .* E[row]; sp = sum tree, mq = max tree; 2 butterflies ----
        double t[8];
        #pragma unroll
        for (int q = 0; q < 8; ++q)
            t[q] = wlds[ph][lane + 64 * q] * treg[q];            // 2-way LDS alias only

        double sp = ((t[0] + t[1]) + (t[2] + t[3])) + ((t[4] + t[5]) + (t[6] + t[7]));
        double mq = fmax(fmax(fmax(t[0], t[1]), fmax(t[2], t[3])),
                         fmax(fmax(t[4], t[5]), fmax(t[6], t[7])));
        #pragma unroll
        for (int off = 32; off; off >>= 1) {
            const double a = __shfl_xor(sp, off);
            const double b = __shfl_xor(mq, off);
            sp += a; mq = fmax(mq, b);
        }

        // publish w' = sp/mq in [1,512] (strictly >1: 512 positive terms); mantissa-LSB tag.
        {
            const double wn = sp / mq;
            uint64_t pk;
            __builtin_memcpy(&pk, &wn, 8);
            pk = (pk & ~1ull) | tag;
            if (lane < REPS)
                AGST(pubbase + (size_t)lane * NTAGS + myrow, pk);
        }

        // ---- pipelined poll of MY single slot (replica bid&7): 4 loads in flight (R0) ----
        if ((p & 1ull) != tag) {
            uint64_t q0 = AGLD(myslot), q1 = AGLD(myslot),
                     q2 = AGLD(myslot), q3 = AGLD(myslot);
            for (;;) {
                if ((q0 & 1ull) == tag) { p = q0; break; }
                q0 = AGLD(myslot);
                if ((q1 & 1ull) == tag) { p = q1; break; }
                q1 = AGLD(myslot);
                if ((q2 & 1ull) == tag) { p = q2; break; }
                q2 = AGLD(myslot);
                if ((q3 & 1ull) == tag) { p = q3; break; }
                q3 = AGLD(myslot);
            }
        }

        // ---- convergence test |w_{s+1}-w_s| <= 1e-9 * w_s (fp64), then rebroadcast ----
        const uint64_t pb = p & ~1ull;                           // clear tag bit (2^-52, det.)
        double nv;
        __builtin_memcpy(&nv, &pb, 8);
        const double old = wlds[ph][tid];
        const int    eq  = (fabs(nv - old) <= CONV_EPS * old);   // old=0 at s=0 -> false
        wlds[nxt][tid] = nv;
        const int e1 = __all(eq);
        if (lane == 0) conv[ph][wave] = e1;
        __syncthreads();   // depth-2 ping-pong: one sync per step suffices (R0)

        // Uniform decision on bit-identical fp64 data -> all waves of ALL blocks break together.
        int c1 = conv[ph][0];
        #pragma unroll
        for (int w2 = 1; w2 < ROWS; ++w2) c1 &= conv[ph][w2];
        if (c1) { sel = nxt; break; }    // w_{s+1} within ~1e-9 of w* ~ w_512
    }

    // ================= terminal by row STOP's wave (block 63, wave 7) ======================
    if (myrow == STOP_TAG) {
        double t[8];
        #pragma unroll
        for (int q = 0; q < 8; ++q)
            t[q] = wlds[sel][lane + 64 * q] * treg[q];           // treg == exp(T[STOP][*])
        double sp = ((t[0] + t[1]) + (t[2] + t[3])) + ((t[4] + t[5]) + (t[6] + t[7]));
        double mq = fmax(fmax(fmax(t[0], t[1]), fmax(t[2], t[3])),
                         fmax(fmax(t[4], t[5]), fmax(t[6], t[7])));
        #pragma unroll
        for (int off = 32; off; off >>= 1) {
            const double a = __shfl_xor(sp, off);
            const double b = __shfl_xor(mq, off);
            sp += a; mq = fmax(mq, b);
        }
        if (lane == 0) {
            while (AGLD(numdone) < BATCH) {}                     // all numerator blocks retired
            const double ld  = log(sp) - log(mq);                // log_denominator (batch-invar.)
            const float  num = AGLD(numacc);
            out[0] = num - (float)((double)BATCH * ld);
        }
    }
}

extern "C" void kernel_launch(void* const* d_in, const int* in_sizes, int n_in,
                              void* d_out, int out_size, void* d_ws, size_t ws_size,
                              hipStream_t stream)
{
    const float* inputs = (const float*)d_in[0];   // (64, 512, 512) fp32
    const int*   tags   = (const int*)  d_in[1];   // (64, 512) int32
    const float* trans  = (const float*)d_in[2];   // (512, 512) fp32
    float* out = (float*)d_out;

    // zero numerator accumulator + done counter + tagged slot buffers
    hipMemsetAsync(d_ws, 0, WS_BYTES, stream);

    crf_fused<<<NBLK, BT, 0, stream>>>(inputs, tags, trans, d_ws, out);
}